// Round 10
// baseline (603.852 us; speedup 1.0000x reference)
//
#include <hip/hip_runtime.h>
#include <math.h>

// ---------------------------------------------------------------------------
// ARMA GNN forward: gcn_norm -> ARMAConv(128->32,K=2,T=2,relu) -> relu ->
//                   ARMAConv(32->40,K=2,T=2) -> log_softmax
// CSC gather propagation, bf16 messages SPLIT INTO FEATURE-HALF PASSES so the
// random-read table fits per-XCD L2 (4MB); streams marked nontemporal.
// Dense GEMMs on MFMA (bf16 weights pre-transposed, L1-resident).
// ---------------------------------------------------------------------------

typedef unsigned short ushort_t;
typedef __attribute__((ext_vector_type(8))) short  short8v;   // 8 bf16 (4 VGPR)
typedef __attribute__((ext_vector_type(4))) float  float4v;   // C/D frag
typedef __attribute__((ext_vector_type(2))) float  f32x2;
typedef __attribute__((ext_vector_type(2))) int    i32x2;

__device__ inline ushort_t f2bf(float v) {           // RNE f32 -> bf16
    unsigned u = __float_as_uint(v);
    u += 0x7FFFu + ((u >> 16) & 1u);
    return (ushort_t)(u >> 16);
}
__device__ inline f32x2 unpack2(unsigned p) {        // 2 packed bf16 -> f32x2
    f32x2 r;
    r[0] = __uint_as_float(p << 16);
    r[1] = __uint_as_float(p & 0xFFFF0000u);
    return r;
}

// ---- CSC build ------------------------------------------------------------
__global__ void k_hist(const int* __restrict__ col, int* __restrict__ deg, int e) {
    int i = blockIdx.x * blockDim.x + threadIdx.x;
    if (i < e) atomicAdd(&deg[col[i]], 1);
}

__global__ void k_dinv(const int* __restrict__ deg, float* __restrict__ dinv, int n) {
    int i = blockIdx.x * blockDim.x + threadIdx.x;
    if (i < n) {
        int d = deg[i];
        dinv[i] = d > 0 ? rsqrtf((float)d) : 0.0f;
    }
}

__global__ void k_scan1(const int* __restrict__ deg, int* __restrict__ start,
                        int* __restrict__ bsum, int n) {
    __shared__ int s[256];
    int t = threadIdx.x, idx = blockIdx.x * 256 + t;
    int v = (idx < n) ? deg[idx] : 0;
    s[t] = v; __syncthreads();
    for (int o = 1; o < 256; o <<= 1) {
        int x = (t >= o) ? s[t - o] : 0;
        __syncthreads(); s[t] += x; __syncthreads();
    }
    if (idx <= n) start[idx] = s[t] - v;
    if (t == 255) bsum[blockIdx.x] = s[255];
}

__global__ void k_scan2(const int* __restrict__ bsum, int* __restrict__ bscan) {
    __shared__ int s[256];
    int t = threadIdx.x;
    int v = bsum[t]; s[t] = v; __syncthreads();
    for (int o = 1; o < 256; o <<= 1) {
        int x = (t >= o) ? s[t - o] : 0;
        __syncthreads(); s[t] += x; __syncthreads();
    }
    bscan[t] = s[t] - v;
}

__global__ void k_scan3(int* __restrict__ start, int* __restrict__ cursor,
                        const int* __restrict__ bscan, int n) {
    int idx = blockIdx.x * 256 + threadIdx.x;
    if (idx <= n) {
        int v = start[idx] + bscan[idx >> 8];
        start[idx] = v;
        if (idx < n) cursor[idx] = v;
    }
}

__global__ void k_sort(const int* __restrict__ row, const int* __restrict__ col,
                       const float* __restrict__ dinv, int* __restrict__ cursor,
                       int2* __restrict__ sedge, int e) {
    int i = blockIdx.x * blockDim.x + threadIdx.x;
    if (i < e) {
        int r = row[i], c = col[i];
        int pos = atomicAdd(&cursor[c], 1);
        sedge[pos] = make_int2(r, __float_as_int(dinv[r] * dinv[c]));
    }
}

// ---- weight prep: Wt[col][k] bf16, col = concat(init k*H+h, root k*H+h) ----
__global__ void k_wprep(const float* __restrict__ wi, const float* __restrict__ wr,
                        ushort_t* __restrict__ Wt, int K, int F, int H) {
    int idx = blockIdx.x * blockDim.x + threadIdx.x;
    int tot = 2 * K * H * F;
    if (idx >= tot) return;
    int f = idx % F, colx = idx / F;
    int KH = K * H;
    const float* src = (colx < KH) ? wi : wr;
    int c = (colx < KH) ? colx : colx - KH;
    int k = c / H, h = c % H;
    Wt[idx] = f2bf(src[((long)k * F + f) * H + h]);
}

// block-diagonal deep weights: Wt[col= k*F+h][kin (padded to FPAD)]
__global__ void k_wprep_diag(const float* __restrict__ w, ushort_t* __restrict__ Wt,
                             int K, int F, int FPAD) {
    int idx = blockIdx.x * blockDim.x + threadIdx.x;
    int tot = K * F * FPAD;
    if (idx >= tot) return;
    int kin = idx % FPAD, colx = idx / FPAD;
    int k = colx / F, h = colx % F;
    float v = 0.0f;
    if (kin < K * F) {
        int kp = kin / F, f = kin % F;
        if (kp == k) v = w[((long)k * F + f) * F + h];
    }
    Wt[idx] = f2bf(v);
}

// ---- MFMA GEMM: C[n, NCOLT*16] = X[n, FIN]_f32 @ Wt^T ----------------------
// A-outputs (cols < KF0) go to half-split layout out0[half][n][HALF] bf16;
// SPLIT: cols >= KF0 -> root[n][KF0] f32.
template<int FIN, int FPAD, int NCOLT, int KF0, int HALF, bool SPLIT>
__global__ void k_mfma_gemm(const float* __restrict__ X,
                            const ushort_t* __restrict__ Wt,
                            ushort_t* __restrict__ out0,
                            float* __restrict__ root,
                            int n) {
    constexpr int KSTEPS = FPAD / 32;
    int wid  = (blockIdx.x * blockDim.x + threadIdx.x) >> 6;
    int lane = threadIdx.x & 63;
    int m0 = wid * 16;
    if (m0 >= n) return;
    int r = lane & 15, g = lane >> 4;        // A row / D col = r ; k-group = g
    float4v acc[NCOLT];
#pragma unroll
    for (int c = 0; c < NCOLT; ++c) acc[c] = (float4v){0.f, 0.f, 0.f, 0.f};
#pragma unroll
    for (int ks = 0; ks < KSTEPS; ++ks) {
        int kb = ks * 32 + g * 8;
        const float* xr = X + (long)(m0 + r) * FIN + kb;
        float4 x0 = *(const float4*)xr;
        float4 x1 = *(const float4*)(xr + 4);
        short8v af;
        af[0] = (short)f2bf(x0.x); af[1] = (short)f2bf(x0.y);
        af[2] = (short)f2bf(x0.z); af[3] = (short)f2bf(x0.w);
        af[4] = (short)f2bf(x1.x); af[5] = (short)f2bf(x1.y);
        af[6] = (short)f2bf(x1.z); af[7] = (short)f2bf(x1.w);
#pragma unroll
        for (int c = 0; c < NCOLT; ++c) {
            short8v bf = *(const short8v*)&Wt[(long)(c * 16 + r) * FPAD + kb];
            acc[c] = __builtin_amdgcn_mfma_f32_16x16x32_bf16(af, bf, acc[c], 0, 0, 0);
        }
    }
#pragma unroll
    for (int c = 0; c < NCOLT; ++c) {
        int colx = c * 16 + r;
#pragma unroll
        for (int i = 0; i < 4; ++i) {
            long node = m0 + g * 4 + i;
            if (!SPLIT || colx < KF0) {
                int hf = colx / HALF, f = colx - hf * HALF;
                out0[((long)hf * n + node) * HALF + f] = f2bf(acc[c][i]);
            } else {
                root[node * KF0 + (colx - KF0)] = acc[c][i];
            }
        }
    }
}

// ---- half-feature gather pass ----------------------------------------------
// Ah: one half-table [n][HALF] bf16 (random reads, keep cached).
// root/bias/out pointers are pre-offset to this pass's feature base.
// MODE 0: plain store; MODE 1: relu store; MODE 3: out = 0.5*(out + relu(acc))
// HALF/2 lanes per node, 2 nodes (dual chain) per thread.
template<int HALF, int MODE>
__global__ void k_gatherH(const ushort_t* __restrict__ Ah, const int2* __restrict__ sedge,
                          const int* __restrict__ start, const float* __restrict__ root,
                          const float* __restrict__ bias, float* __restrict__ out,
                          int rootStride, int outStride, int npairs) {
    constexpr int LPN = HALF / 2;
    const unsigned* A32 = (const unsigned*)Ah;
    int gid = blockIdx.x * blockDim.x + threadIdx.x;
    int q = gid / LPN, sub = gid % LPN;
    if (q >= npairs) return;
    int na = 2 * q, nb = 2 * q + 1;
    f32x2 bi   = *(const f32x2*)&bias[2 * sub];
    f32x2 acca = __builtin_nontemporal_load((const f32x2*)&root[(long)na * rootStride + 2 * sub]);
    f32x2 accb = __builtin_nontemporal_load((const f32x2*)&root[(long)nb * rootStride + 2 * sub]);
    acca += bi; accb += bi;
    int ea = start[na], e1a = start[na + 1];
    int eb = start[nb], e1b = start[nb + 1];
    while (ea < e1a && eb < e1b) {
        i32x2 pa = __builtin_nontemporal_load((const i32x2*)(sedge + ea));
        i32x2 pb = __builtin_nontemporal_load((const i32x2*)(sedge + eb));
        f32x2 va = unpack2(A32[(long)pa[0] * LPN + sub]);
        f32x2 vb = unpack2(A32[(long)pb[0] * LPN + sub]);
        float wa = __int_as_float(pa[1]), wb = __int_as_float(pb[1]);
        acca[0] = fmaf(va[0], wa, acca[0]); acca[1] = fmaf(va[1], wa, acca[1]);
        accb[0] = fmaf(vb[0], wb, accb[0]); accb[1] = fmaf(vb[1], wb, accb[1]);
        ++ea; ++eb;
    }
    for (; ea < e1a; ++ea) {
        i32x2 p = __builtin_nontemporal_load((const i32x2*)(sedge + ea));
        f32x2 v = unpack2(A32[(long)p[0] * LPN + sub]);
        float w = __int_as_float(p[1]);
        acca[0] = fmaf(v[0], w, acca[0]); acca[1] = fmaf(v[1], w, acca[1]);
    }
    for (; eb < e1b; ++eb) {
        i32x2 p = __builtin_nontemporal_load((const i32x2*)(sedge + eb));
        f32x2 v = unpack2(A32[(long)p[0] * LPN + sub]);
        float w = __int_as_float(p[1]);
        accb[0] = fmaf(v[0], w, accb[0]); accb[1] = fmaf(v[1], w, accb[1]);
    }
    float* oa = out + (long)na * outStride + 2 * sub;
    float* ob = out + (long)nb * outStride + 2 * sub;
    if (MODE == 0) {
        __builtin_nontemporal_store(acca, (f32x2*)oa);
        __builtin_nontemporal_store(accb, (f32x2*)ob);
    } else if (MODE == 1) {
        f32x2 ra, rb;
        ra[0] = fmaxf(acca[0], 0.f); ra[1] = fmaxf(acca[1], 0.f);
        rb[0] = fmaxf(accb[0], 0.f); rb[1] = fmaxf(accb[1], 0.f);
        __builtin_nontemporal_store(ra, (f32x2*)oa);
        __builtin_nontemporal_store(rb, (f32x2*)ob);
    } else {
        f32x2 pa = *(const f32x2*)oa;
        f32x2 pb = *(const f32x2*)ob;
        f32x2 ra, rb;
        ra[0] = 0.5f * (pa[0] + fmaxf(acca[0], 0.f));
        ra[1] = 0.5f * (pa[1] + fmaxf(acca[1], 0.f));
        rb[0] = 0.5f * (pb[0] + fmaxf(accb[0], 0.f));
        rb[1] = 0.5f * (pb[1] + fmaxf(accb[1], 0.f));
        __builtin_nontemporal_store(ra, (f32x2*)oa);
        __builtin_nontemporal_store(rb, (f32x2*)ob);
    }
}

// ---- conv2 epilogue: mean over K + row log_softmax (40 classes) ------------
__global__ void k_logsoftmax(const float* __restrict__ B, float* __restrict__ out, int n) {
    int gid  = blockIdx.x * blockDim.x + threadIdx.x;
    int wave = gid >> 6;
    int lane = gid & 63;
    if (wave >= n) return;
    float v = -INFINITY;
    if (lane < 40)
        v = 0.5f * (B[(long)wave * 80 + lane] + B[(long)wave * 80 + 40 + lane]);
    float m = v;
#pragma unroll
    for (int o = 32; o; o >>= 1) m = fmaxf(m, __shfl_xor(m, o));
    float ex = (lane < 40) ? expf(v - m) : 0.0f;
    float s = ex;
#pragma unroll
    for (int o = 32; o; o >>= 1) s += __shfl_xor(s, o);
    if (lane < 40) out[(long)wave * 40 + lane] = v - m - logf(s);
}

// ---------------------------------------------------------------------------
extern "C" void kernel_launch(void* const* d_in, const int* in_sizes, int n_in,
                              void* d_out, int out_size, void* d_ws, size_t ws_size,
                              hipStream_t stream) {
    const float* x       = (const float*)d_in[0];
    const int*   eidx    = (const int*)d_in[1];
    const float* w1_init = (const float*)d_in[2];
    const float* w1_deep = (const float*)d_in[3];
    const float* w1_root = (const float*)d_in[4];
    const float* b1      = (const float*)d_in[5];
    const float* w2_init = (const float*)d_in[6];
    const float* w2_deep = (const float*)d_in[7];
    const float* w2_root = (const float*)d_in[8];
    const float* b2      = (const float*)d_in[9];
    float* out = (float*)d_out;

    const int N = in_sizes[0] / 128;
    const int E = in_sizes[1] / 2;
    const int* row = eidx;
    const int* col = eidx + E;

    // workspace layout
    int2*     sedge  = (int2*)d_ws;                   // E
    int*      start  = (int*)(sedge + E);             // N+4 (padded for align)
    ushort_t* A      = (ushort_t*)(start + N + 4);    // [2][N][HALF<=40] bf16
    float*    B      = (float*)(A + (long)N * 80);    // N*80 f32
    float*    root   = B + (long)N * 80;              // N*80 f32
    ushort_t* Wt1    = (ushort_t*)(root + (long)N * 80); // 128*128 bf16
    ushort_t* Wt2    = Wt1 + 128 * 128;               // 160*32
    ushort_t* Wtd1   = Wt2 + 160 * 32;                // 64*64
    ushort_t* Wtd2   = Wtd1 + 64 * 64;                // 80*96
    int*      deg_i  = (int*)(Wtd2 + 80 * 96);        // N   (transient)
    int*      cursor = deg_i + N;                     // N   (transient)
    int*      bsum   = cursor + N;                    // 256 (transient)
    int*      bscan  = bsum + 256;                    // 256 (transient)
    float*    dinv   = (float*)(bscan + 256);         // N   (transient)
    float*    h      = B;                             // N*32 f32, aliases B

    const int BS = 256;
    auto cdiv = [](long a, long b) { return (int)((a + b - 1) / b); };
    const int NP = N / 2;          // node pairs (N even)
    const int MT = cdiv(N, 16);    // M-tiles (N % 16 == 0)

    // ---- CSC build + weight prep ----
    hipMemsetAsync(deg_i, 0, (size_t)N * 4, stream);
    k_hist<<<cdiv(E, BS), BS, 0, stream>>>(col, deg_i, E);
    k_dinv<<<cdiv(N, BS), BS, 0, stream>>>(deg_i, dinv, N);
    k_scan1<<<256, 256, 0, stream>>>(deg_i, start, bsum, N);
    k_scan2<<<1, 256, 0, stream>>>(bsum, bscan);
    k_scan3<<<256, 256, 0, stream>>>(start, cursor, bscan, N);
    k_sort<<<cdiv(E, BS), BS, 0, stream>>>(row, col, dinv, cursor, sedge, E);
    k_wprep<<<cdiv(2 * 2 * 32 * 128, BS), BS, 0, stream>>>(w1_init, w1_root, Wt1, 2, 128, 32);
    k_wprep<<<cdiv(2 * 2 * 40 * 32, BS), BS, 0, stream>>>(w2_init, w2_root, Wt2, 2, 32, 40);
    k_wprep_diag<<<cdiv(64 * 64, BS), BS, 0, stream>>>(w1_deep, Wtd1, 2, 32, 64);
    k_wprep_diag<<<cdiv(80 * 96, BS), BS, 0, stream>>>(w2_deep, Wtd2, 2, 40, 96);

    ushort_t* Alo64 = A;                    // [N][32] (stack 0)
    ushort_t* Ahi64 = A + (long)N * 32;     // [N][32] (stack 1)
    ushort_t* Alo80 = A;                    // [N][40] (stack 0)
    ushort_t* Ahi80 = A + (long)N * 40;     // [N][40] (stack 1)
    const int G64 = cdiv((long)NP * 16, BS);      // threads: 16 lanes/pair
    const int G80 = cdiv((long)NP * 20, 320);     // threads: 20 lanes/pair

    // ---- conv1: 128 -> 32, K=2 (KF=64), relu ----
    k_mfma_gemm<128, 128, 8, 64, 32, true><<<cdiv(MT, 4), 256, 0, stream>>>(x, Wt1, A, root, N);
    k_gatherH<32, 1><<<G64, BS, 0, stream>>>(Alo64, sedge, start, root,      b1,      B,      64, 64, NP);
    k_gatherH<32, 1><<<G64, BS, 0, stream>>>(Ahi64, sedge, start, root + 32, b1 + 32, B + 32, 64, 64, NP);
    k_mfma_gemm<64, 64, 4, 64, 32, false><<<cdiv(MT, 4), 256, 0, stream>>>(B, Wtd1, A, nullptr, N);
    k_gatherH<32, 1><<<G64, BS, 0, stream>>>(Alo64, sedge, start, root,      b1,      h,      64, 32, NP);
    k_gatherH<32, 3><<<G64, BS, 0, stream>>>(Ahi64, sedge, start, root + 32, b1 + 32, h,      64, 32, NP);

    // ---- conv2: 32 -> 40, K=2 (KF=80), no act ----
    k_mfma_gemm<32, 32, 10, 80, 40, true><<<cdiv(MT, 4), 256, 0, stream>>>(h, Wt2, A, root, N);
    k_gatherH<40, 0><<<G80, 320, 0, stream>>>(Alo80, sedge, start, root,      b2,      B,      80, 80, NP);
    k_gatherH<40, 0><<<G80, 320, 0, stream>>>(Ahi80, sedge, start, root + 40, b2 + 40, B + 40, 80, 80, NP);
    k_mfma_gemm<80, 96, 5, 80, 40, false><<<cdiv(MT, 4), 256, 0, stream>>>(B, Wtd2, A, nullptr, N);
    k_gatherH<40, 0><<<G80, 320, 0, stream>>>(Alo80, sedge, start, root,      b2,      B,      80, 80, NP);
    k_gatherH<40, 0><<<G80, 320, 0, stream>>>(Ahi80, sedge, start, root + 40, b2 + 40, B + 40, 80, 80, NP);

    // ---- epilogue: mean over K + log_softmax ----
    k_logsoftmax<<<cdiv((long)N * 64, BS), BS, 0, stream>>>(B, out, N);
}

// Round 11
// 511.312 us; speedup vs baseline: 1.1810x; 1.1810x over previous
//
#include <hip/hip_runtime.h>
#include <math.h>

// ---------------------------------------------------------------------------
// ARMA GNN forward: gcn_norm -> ARMAConv(128->32,K=2,T=2,relu) -> relu ->
//                   ARMAConv(32->40,K=2,T=2) -> log_softmax
// CSC gather propagation. Messages/root/intermediates bf16 (traffic), quad
// independent load chains per lane (MLP). Dense GEMMs on MFMA.
// ---------------------------------------------------------------------------

typedef unsigned short ushort_t;
typedef __attribute__((ext_vector_type(8))) short  short8v;   // 8 bf16 (4 VGPR)
typedef __attribute__((ext_vector_type(4))) float  float4v;   // C/D frag
typedef __attribute__((ext_vector_type(2))) float  f32x2;
typedef __attribute__((ext_vector_type(2))) int    i32x2;

__device__ inline ushort_t f2bf(float v) {           // RNE f32 -> bf16
    unsigned u = __float_as_uint(v);
    u += 0x7FFFu + ((u >> 16) & 1u);
    return (ushort_t)(u >> 16);
}
__device__ inline f32x2 unpack2(unsigned p) {        // 2 packed bf16 -> f32x2
    f32x2 r;
    r[0] = __uint_as_float(p << 16);
    r[1] = __uint_as_float(p & 0xFFFF0000u);
    return r;
}

// ---- CSC build ------------------------------------------------------------
__global__ void k_hist(const int* __restrict__ col, int* __restrict__ deg, int e) {
    int i = blockIdx.x * blockDim.x + threadIdx.x;
    if (i < e) atomicAdd(&deg[col[i]], 1);
}

__global__ void k_dinv(const int* __restrict__ deg, float* __restrict__ dinv, int n) {
    int i = blockIdx.x * blockDim.x + threadIdx.x;
    if (i < n) {
        int d = deg[i];
        dinv[i] = d > 0 ? rsqrtf((float)d) : 0.0f;
    }
}

__global__ void k_scan1(const int* __restrict__ deg, int* __restrict__ start,
                        int* __restrict__ bsum, int n) {
    __shared__ int s[256];
    int t = threadIdx.x, idx = blockIdx.x * 256 + t;
    int v = (idx < n) ? deg[idx] : 0;
    s[t] = v; __syncthreads();
    for (int o = 1; o < 256; o <<= 1) {
        int x = (t >= o) ? s[t - o] : 0;
        __syncthreads(); s[t] += x; __syncthreads();
    }
    if (idx <= n) start[idx] = s[t] - v;
    if (t == 255) bsum[blockIdx.x] = s[255];
}

__global__ void k_scan2(const int* __restrict__ bsum, int* __restrict__ bscan) {
    __shared__ int s[256];
    int t = threadIdx.x;
    int v = bsum[t]; s[t] = v; __syncthreads();
    for (int o = 1; o < 256; o <<= 1) {
        int x = (t >= o) ? s[t - o] : 0;
        __syncthreads(); s[t] += x; __syncthreads();
    }
    bscan[t] = s[t] - v;
}

__global__ void k_scan3(int* __restrict__ start, int* __restrict__ cursor,
                        const int* __restrict__ bscan, int n) {
    int idx = blockIdx.x * 256 + threadIdx.x;
    if (idx <= n) {
        int v = start[idx] + bscan[idx >> 8];
        start[idx] = v;
        if (idx < n) cursor[idx] = v;
    }
}

__global__ void k_sort(const int* __restrict__ row, const int* __restrict__ col,
                       const float* __restrict__ dinv, int* __restrict__ cursor,
                       int2* __restrict__ sedge, int e) {
    int i = blockIdx.x * blockDim.x + threadIdx.x;
    if (i < e) {
        int r = row[i], c = col[i];
        int pos = atomicAdd(&cursor[c], 1);
        sedge[pos] = make_int2(r, __float_as_int(dinv[r] * dinv[c]));
    }
}

// ---- weight prep: Wt[col][k] bf16, col = concat(init k*H+h, root k*H+h) ----
__global__ void k_wprep(const float* __restrict__ wi, const float* __restrict__ wr,
                        ushort_t* __restrict__ Wt, int K, int F, int H) {
    int idx = blockIdx.x * blockDim.x + threadIdx.x;
    int tot = 2 * K * H * F;
    if (idx >= tot) return;
    int f = idx % F, colx = idx / F;
    int KH = K * H;
    const float* src = (colx < KH) ? wi : wr;
    int c = (colx < KH) ? colx : colx - KH;
    int k = c / H, h = c % H;
    Wt[idx] = f2bf(src[((long)k * F + f) * H + h]);
}

// block-diagonal deep weights: Wt[col= k*F+h][kin (padded to FPAD)]
__global__ void k_wprep_diag(const float* __restrict__ w, ushort_t* __restrict__ Wt,
                             int K, int F, int FPAD) {
    int idx = blockIdx.x * blockDim.x + threadIdx.x;
    int tot = K * F * FPAD;
    if (idx >= tot) return;
    int kin = idx % FPAD, colx = idx / FPAD;
    int k = colx / F, h = colx % F;
    float v = 0.0f;
    if (kin < K * F) {
        int kp = kin / F, f = kin % F;
        if (kp == k) v = w[((long)k * F + f) * F + h];
    }
    Wt[idx] = f2bf(v);
}

// ---- MFMA GEMM: C[n, NCOLT*16] = X[n, FIN] @ Wt^T --------------------------
// XT = float or ushort_t (bf16). SPLIT: cols >= KF0 -> rootb bf16.
template<typename XT, int FIN, int FPAD, int NCOLT, int KF0, bool SPLIT>
__global__ void k_mfma_gemm(const XT* __restrict__ X,
                            const ushort_t* __restrict__ Wt,
                            ushort_t* __restrict__ out0,
                            ushort_t* __restrict__ rootb,
                            int n) {
    constexpr int KSTEPS = FPAD / 32;
    int wid  = (blockIdx.x * blockDim.x + threadIdx.x) >> 6;
    int lane = threadIdx.x & 63;
    int m0 = wid * 16;
    if (m0 >= n) return;
    int r = lane & 15, g = lane >> 4;        // A row / D col = r ; k-group = g
    float4v acc[NCOLT];
#pragma unroll
    for (int c = 0; c < NCOLT; ++c) acc[c] = (float4v){0.f, 0.f, 0.f, 0.f};
#pragma unroll
    for (int ks = 0; ks < KSTEPS; ++ks) {
        int kb = ks * 32 + g * 8;
        short8v af;
        if constexpr (sizeof(XT) == 2) {
            af = *(const short8v*)&X[(long)(m0 + r) * FIN + kb];
        } else {
            const float* xr = (const float*)X + (long)(m0 + r) * FIN + kb;
            float4 x0 = *(const float4*)xr;
            float4 x1 = *(const float4*)(xr + 4);
            af[0] = (short)f2bf(x0.x); af[1] = (short)f2bf(x0.y);
            af[2] = (short)f2bf(x0.z); af[3] = (short)f2bf(x0.w);
            af[4] = (short)f2bf(x1.x); af[5] = (short)f2bf(x1.y);
            af[6] = (short)f2bf(x1.z); af[7] = (short)f2bf(x1.w);
        }
#pragma unroll
        for (int c = 0; c < NCOLT; ++c) {
            short8v bf = *(const short8v*)&Wt[(long)(c * 16 + r) * FPAD + kb];
            acc[c] = __builtin_amdgcn_mfma_f32_16x16x32_bf16(af, bf, acc[c], 0, 0, 0);
        }
    }
#pragma unroll
    for (int c = 0; c < NCOLT; ++c) {
        int colx = c * 16 + r;
#pragma unroll
        for (int i = 0; i < 4; ++i) {
            long node = m0 + g * 4 + i;
            ushort_t val = f2bf(acc[c][i]);
            if (!SPLIT || colx < KF0)
                out0[node * KF0 + colx] = val;
            else
                rootb[node * KF0 + (colx - KF0)] = val;
        }
    }
}

// ---- quad-chain gather: LPN lanes/node (2 bf16 feats each), 4 nodes/thread -
// A, root bf16. MODE 0: store bf16; 1: relu bf16; 2: relu+mean K=2 -> bf16
// [n][32] (LPN=32 only, shfl_xor 16); 3: store f32 (final, for logsoftmax).
template<int LPN, int MODE>
__global__ void k_gatherQ(const ushort_t* __restrict__ A, const int2* __restrict__ sedge,
                          const int* __restrict__ start, const ushort_t* __restrict__ root,
                          const float* __restrict__ bias, void* __restrict__ outv, int nq) {
    const unsigned* A32 = (const unsigned*)A;
    const unsigned* R32 = (const unsigned*)root;
    int gid = blockIdx.x * blockDim.x + threadIdx.x;
    int q = gid / LPN, sub = gid % LPN;
    if (q >= nq) return;
    int n0 = 4 * q;
    f32x2 bi = *(const f32x2*)&bias[2 * sub];
    f32x2 acc[4];
    int e0[4], e1[4];
#pragma unroll
    for (int j = 0; j < 4; ++j) {
        unsigned rp = __builtin_nontemporal_load(&R32[(long)(n0 + j) * LPN + sub]);
        acc[j] = unpack2(rp) + bi;
        e0[j] = start[n0 + j];
        e1[j] = start[n0 + j + 1];
    }
    while (e0[0] < e1[0] && e0[1] < e1[1] && e0[2] < e1[2] && e0[3] < e1[3]) {
#pragma unroll
        for (int j = 0; j < 4; ++j) {
            i32x2 p = __builtin_nontemporal_load((const i32x2*)(sedge + e0[j]));
            f32x2 v = unpack2(A32[(long)p[0] * LPN + sub]);
            float w = __int_as_float(p[1]);
            acc[j][0] = fmaf(v[0], w, acc[j][0]);
            acc[j][1] = fmaf(v[1], w, acc[j][1]);
            ++e0[j];
        }
    }
#pragma unroll
    for (int j = 0; j < 4; ++j) {
        for (; e0[j] < e1[j]; ++e0[j]) {
            i32x2 p = __builtin_nontemporal_load((const i32x2*)(sedge + e0[j]));
            f32x2 v = unpack2(A32[(long)p[0] * LPN + sub]);
            float w = __int_as_float(p[1]);
            acc[j][0] = fmaf(v[0], w, acc[j][0]);
            acc[j][1] = fmaf(v[1], w, acc[j][1]);
        }
    }
    if (MODE == 3) {
        float* out = (float*)outv;
#pragma unroll
        for (int j = 0; j < 4; ++j)
            __builtin_nontemporal_store(acc[j], (f32x2*)&out[(long)(n0 + j) * 2 * LPN + 2 * sub]);
    } else if (MODE == 2) {
        unsigned* out = (unsigned*)outv;
#pragma unroll
        for (int j = 0; j < 4; ++j) {
            float v0 = fmaxf(acc[j][0], 0.f), v1 = fmaxf(acc[j][1], 0.f);
            float o0 = __shfl_xor(v0, 16), o1 = __shfl_xor(v1, 16);
            if (sub < 16) {
                unsigned pk = (unsigned)f2bf(0.5f * (v0 + o0)) |
                              ((unsigned)f2bf(0.5f * (v1 + o1)) << 16);
                __builtin_nontemporal_store(pk, &out[(long)(n0 + j) * 16 + sub]);
            }
        }
    } else {
        unsigned* out = (unsigned*)outv;
#pragma unroll
        for (int j = 0; j < 4; ++j) {
            float v0 = acc[j][0], v1 = acc[j][1];
            if (MODE == 1) { v0 = fmaxf(v0, 0.f); v1 = fmaxf(v1, 0.f); }
            unsigned pk = (unsigned)f2bf(v0) | ((unsigned)f2bf(v1) << 16);
            __builtin_nontemporal_store(pk, &out[(long)(n0 + j) * LPN + sub]);
        }
    }
}

// ---- conv2 epilogue: mean over K + row log_softmax (40 classes) ------------
__global__ void k_logsoftmax(const float* __restrict__ B, float* __restrict__ out, int n) {
    int gid  = blockIdx.x * blockDim.x + threadIdx.x;
    int wave = gid >> 6;
    int lane = gid & 63;
    if (wave >= n) return;
    float v = -INFINITY;
    if (lane < 40)
        v = 0.5f * (B[(long)wave * 80 + lane] + B[(long)wave * 80 + 40 + lane]);
    float m = v;
#pragma unroll
    for (int o = 32; o; o >>= 1) m = fmaxf(m, __shfl_xor(m, o));
    float ex = (lane < 40) ? expf(v - m) : 0.0f;
    float s = ex;
#pragma unroll
    for (int o = 32; o; o >>= 1) s += __shfl_xor(s, o);
    if (lane < 40) out[(long)wave * 40 + lane] = v - m - logf(s);
}

// ---------------------------------------------------------------------------
extern "C" void kernel_launch(void* const* d_in, const int* in_sizes, int n_in,
                              void* d_out, int out_size, void* d_ws, size_t ws_size,
                              hipStream_t stream) {
    const float* x       = (const float*)d_in[0];
    const int*   eidx    = (const int*)d_in[1];
    const float* w1_init = (const float*)d_in[2];
    const float* w1_deep = (const float*)d_in[3];
    const float* w1_root = (const float*)d_in[4];
    const float* b1      = (const float*)d_in[5];
    const float* w2_init = (const float*)d_in[6];
    const float* w2_deep = (const float*)d_in[7];
    const float* w2_root = (const float*)d_in[8];
    const float* b2      = (const float*)d_in[9];
    float* out = (float*)d_out;

    const int N = in_sizes[0] / 128;
    const int E = in_sizes[1] / 2;
    const int* row = eidx;
    const int* col = eidx + E;

    // workspace layout (bf16 tables first; Bh followed by rootb so deep2's
    // padded-K overrun reads stay in-bounds)
    int2*     sedge  = (int2*)d_ws;                   // E
    int*      start  = (int*)(sedge + E);             // N+8 (padded for align)
    ushort_t* A      = (ushort_t*)(start + N + 8);    // [N][<=80] bf16 messages
    ushort_t* Bh     = A + (long)N * 80;              // [N][<=80] bf16 gather out
    ushort_t* rootb  = Bh + (long)N * 80;             // [N][<=80] bf16 root
    float*    Bf     = (float*)(rootb + (long)N * 80);// [N][80] f32 (final only)
    ushort_t* Wt1    = (ushort_t*)(Bf + (long)N * 80);// 128*128 bf16
    ushort_t* Wt2    = Wt1 + 128 * 128;               // 160*32
    ushort_t* Wtd1   = Wt2 + 160 * 32;                // 64*64
    ushort_t* Wtd2   = Wtd1 + 64 * 64;                // 80*96
    int*      deg_i  = (int*)(Wtd2 + 80 * 96);        // N   (transient)
    int*      cursor = deg_i + N;                     // N   (transient)
    int*      bsum   = cursor + N;                    // 256 (transient)
    int*      bscan  = bsum + 256;                    // 256 (transient)
    float*    dinv   = (float*)(bscan + 256);         // N   (transient)
    ushort_t* h      = Bh;                            // [N][32] bf16, aliases Bh

    const int BS = 256;
    auto cdiv = [](long a, long b) { return (int)((a + b - 1) / b); };
    const int NQ = N / 4;          // node quads (N % 4 == 0)
    const int MT = cdiv(N, 16);    // M-tiles (N % 16 == 0)

    // ---- CSC build + weight prep ----
    hipMemsetAsync(deg_i, 0, (size_t)N * 4, stream);
    k_hist<<<cdiv(E, BS), BS, 0, stream>>>(col, deg_i, E);
    k_dinv<<<cdiv(N, BS), BS, 0, stream>>>(deg_i, dinv, N);
    k_scan1<<<256, 256, 0, stream>>>(deg_i, start, bsum, N);
    k_scan2<<<1, 256, 0, stream>>>(bsum, bscan);
    k_scan3<<<256, 256, 0, stream>>>(start, cursor, bscan, N);
    k_sort<<<cdiv(E, BS), BS, 0, stream>>>(row, col, dinv, cursor, sedge, E);
    k_wprep<<<cdiv(2 * 2 * 32 * 128, BS), BS, 0, stream>>>(w1_init, w1_root, Wt1, 2, 128, 32);
    k_wprep<<<cdiv(2 * 2 * 40 * 32, BS), BS, 0, stream>>>(w2_init, w2_root, Wt2, 2, 32, 40);
    k_wprep_diag<<<cdiv(64 * 64, BS), BS, 0, stream>>>(w1_deep, Wtd1, 2, 32, 64);
    k_wprep_diag<<<cdiv(80 * 96, BS), BS, 0, stream>>>(w2_deep, Wtd2, 2, 40, 96);

    // ---- conv1: 128 -> 32, K=2 (KF=64), relu ----
    k_mfma_gemm<float, 128, 128, 8, 64, true><<<cdiv(MT, 4), 256, 0, stream>>>(x, Wt1, A, rootb, N);
    k_gatherQ<32, 1><<<cdiv((long)NQ * 32, BS), BS, 0, stream>>>(A, sedge, start, rootb, b1, Bh, NQ);
    k_mfma_gemm<ushort_t, 64, 64, 4, 64, false><<<cdiv(MT, 4), 256, 0, stream>>>(Bh, Wtd1, A, nullptr, N);
    k_gatherQ<32, 2><<<cdiv((long)NQ * 32, BS), BS, 0, stream>>>(A, sedge, start, rootb, b1, h, NQ);

    // ---- conv2: 32 -> 40, K=2 (KF=80), no act ----
    k_mfma_gemm<ushort_t, 32, 32, 10, 80, true><<<cdiv(MT, 4), 256, 0, stream>>>(h, Wt2, A, rootb, N);
    k_gatherQ<40, 0><<<cdiv((long)NQ * 40, 320), 320, 0, stream>>>(A, sedge, start, rootb, b2, Bh, NQ);
    k_mfma_gemm<ushort_t, 80, 96, 5, 80, false><<<cdiv(MT, 4), 256, 0, stream>>>(Bh, Wtd2, A, nullptr, N);
    k_gatherQ<40, 3><<<cdiv((long)NQ * 40, 320), 320, 0, stream>>>(A, sedge, start, rootb, b2, Bf, NQ);

    // ---- epilogue: mean over K + log_softmax ----
    k_logsoftmax<<<cdiv((long)N * 64, BS), BS, 0, stream>>>(Bf, out, N);
}

// Round 13
// 434.437 us; speedup vs baseline: 1.3900x; 1.1770x over previous
//
#include <hip/hip_runtime.h>
#include <math.h>

// ---------------------------------------------------------------------------
// ARMA GNN forward: gcn_norm -> ARMAConv(128->32,K=2,T=2,relu) -> relu ->
//                   ARMAConv(32->40,K=2,T=2) -> log_softmax
// CSC gather propagation: DUAL-chain (measured MLP sweet spot), plain cached
// loads; bf16 messages/root/intermediates. Dense GEMMs on MFMA.
// ---------------------------------------------------------------------------

typedef unsigned short ushort_t;
typedef __attribute__((ext_vector_type(8))) short  short8v;   // 8 bf16 (4 VGPR)
typedef __attribute__((ext_vector_type(4))) float  float4v;   // C/D frag
typedef __attribute__((ext_vector_type(2))) float  f32x2;

__device__ inline ushort_t f2bf(float v) {           // RNE f32 -> bf16
    unsigned u = __float_as_uint(v);
    u += 0x7FFFu + ((u >> 16) & 1u);
    return (ushort_t)(u >> 16);
}
__device__ inline f32x2 unpack2(unsigned p) {        // 2 packed bf16 -> f32x2
    f32x2 r;
    r[0] = __uint_as_float(p << 16);
    r[1] = __uint_as_float(p & 0xFFFF0000u);
    return r;
}

// ---- CSC build ------------------------------------------------------------
__global__ void k_hist(const int* __restrict__ col, int* __restrict__ deg, int e) {
    int i = blockIdx.x * blockDim.x + threadIdx.x;
    if (i < e) atomicAdd(&deg[col[i]], 1);
}

__global__ void k_dinv(const int* __restrict__ deg, float* __restrict__ dinv, int n) {
    int i = blockIdx.x * blockDim.x + threadIdx.x;
    if (i < n) {
        int d = deg[i];
        dinv[i] = d > 0 ? rsqrtf((float)d) : 0.0f;
    }
}

__global__ void k_scan1(const int* __restrict__ deg, int* __restrict__ start,
                        int* __restrict__ bsum, int n) {
    __shared__ int s[256];
    int t = threadIdx.x, idx = blockIdx.x * 256 + t;
    int v = (idx < n) ? deg[idx] : 0;
    s[t] = v; __syncthreads();
    for (int o = 1; o < 256; o <<= 1) {
        int x = (t >= o) ? s[t - o] : 0;
        __syncthreads(); s[t] += x; __syncthreads();
    }
    if (idx <= n) start[idx] = s[t] - v;
    if (t == 255) bsum[blockIdx.x] = s[255];
}

__global__ void k_scan2(const int* __restrict__ bsum, int* __restrict__ bscan) {
    __shared__ int s[256];
    int t = threadIdx.x;
    int v = bsum[t]; s[t] = v; __syncthreads();
    for (int o = 1; o < 256; o <<= 1) {
        int x = (t >= o) ? s[t - o] : 0;
        __syncthreads(); s[t] += x; __syncthreads();
    }
    bscan[t] = s[t] - v;
}

__global__ void k_scan3(int* __restrict__ start, int* __restrict__ cursor,
                        const int* __restrict__ bscan, int n) {
    int idx = blockIdx.x * 256 + threadIdx.x;
    if (idx <= n) {
        int v = start[idx] + bscan[idx >> 8];
        start[idx] = v;
        if (idx < n) cursor[idx] = v;
    }
}

__global__ void k_sort(const int* __restrict__ row, const int* __restrict__ col,
                       const float* __restrict__ dinv, int* __restrict__ cursor,
                       int2* __restrict__ sedge, int e) {
    int i = blockIdx.x * blockDim.x + threadIdx.x;
    if (i < e) {
        int r = row[i], c = col[i];
        int pos = atomicAdd(&cursor[c], 1);
        sedge[pos] = make_int2(r, __float_as_int(dinv[r] * dinv[c]));
    }
}

// ---- weight prep: Wt[col][k] bf16, col = concat(init k*H+h, root k*H+h) ----
__global__ void k_wprep(const float* __restrict__ wi, const float* __restrict__ wr,
                        ushort_t* __restrict__ Wt, int K, int F, int H) {
    int idx = blockIdx.x * blockDim.x + threadIdx.x;
    int tot = 2 * K * H * F;
    if (idx >= tot) return;
    int f = idx % F, colx = idx / F;
    int KH = K * H;
    const float* src = (colx < KH) ? wi : wr;
    int c = (colx < KH) ? colx : colx - KH;
    int k = c / H, h = c % H;
    Wt[idx] = f2bf(src[((long)k * F + f) * H + h]);
}

// block-diagonal deep weights: Wt[col= k*F+h][kin (padded to FPAD)]
__global__ void k_wprep_diag(const float* __restrict__ w, ushort_t* __restrict__ Wt,
                             int K, int F, int FPAD) {
    int idx = blockIdx.x * blockDim.x + threadIdx.x;
    int tot = K * F * FPAD;
    if (idx >= tot) return;
    int kin = idx % FPAD, colx = idx / FPAD;
    int k = colx / F, h = colx % F;
    float v = 0.0f;
    if (kin < K * F) {
        int kp = kin / F, f = kin % F;
        if (kp == k) v = w[((long)k * F + f) * F + h];
    }
    Wt[idx] = f2bf(v);
}

// ---- MFMA GEMM: C[n, NCOLT*16] = X[n, FIN] @ Wt^T --------------------------
// XT = float or ushort_t (bf16). SPLIT: cols >= KF0 -> rootb bf16.
template<typename XT, int FIN, int FPAD, int NCOLT, int KF0, bool SPLIT>
__global__ void k_mfma_gemm(const XT* __restrict__ X,
                            const ushort_t* __restrict__ Wt,
                            ushort_t* __restrict__ out0,
                            ushort_t* __restrict__ rootb,
                            int n) {
    constexpr int KSTEPS = FPAD / 32;
    int wid  = (blockIdx.x * blockDim.x + threadIdx.x) >> 6;
    int lane = threadIdx.x & 63;
    int m0 = wid * 16;
    if (m0 >= n) return;
    int r = lane & 15, g = lane >> 4;        // A row / D col = r ; k-group = g
    float4v acc[NCOLT];
#pragma unroll
    for (int c = 0; c < NCOLT; ++c) acc[c] = (float4v){0.f, 0.f, 0.f, 0.f};
#pragma unroll
    for (int ks = 0; ks < KSTEPS; ++ks) {
        int kb = ks * 32 + g * 8;
        short8v af;
        if constexpr (sizeof(XT) == 2) {
            af = *(const short8v*)&X[(long)(m0 + r) * FIN + kb];
        } else {
            const float* xr = (const float*)X + (long)(m0 + r) * FIN + kb;
            float4 x0 = *(const float4*)xr;
            float4 x1 = *(const float4*)(xr + 4);
            af[0] = (short)f2bf(x0.x); af[1] = (short)f2bf(x0.y);
            af[2] = (short)f2bf(x0.z); af[3] = (short)f2bf(x0.w);
            af[4] = (short)f2bf(x1.x); af[5] = (short)f2bf(x1.y);
            af[6] = (short)f2bf(x1.z); af[7] = (short)f2bf(x1.w);
        }
#pragma unroll
        for (int c = 0; c < NCOLT; ++c) {
            short8v bf = *(const short8v*)&Wt[(long)(c * 16 + r) * FPAD + kb];
            acc[c] = __builtin_amdgcn_mfma_f32_16x16x32_bf16(af, bf, acc[c], 0, 0, 0);
        }
    }
#pragma unroll
    for (int c = 0; c < NCOLT; ++c) {
        int colx = c * 16 + r;
#pragma unroll
        for (int i = 0; i < 4; ++i) {
            long node = m0 + g * 4 + i;
            ushort_t val = f2bf(acc[c][i]);
            if (!SPLIT || colx < KF0)
                out0[node * KF0 + colx] = val;
            else
                rootb[node * KF0 + (colx - KF0)] = val;
        }
    }
}

// ---- dual-chain gather: LPN lanes/node (2 bf16 feats each), 2 nodes/thread -
// A, root bf16; plain cached loads (dual chain = measured MLP sweet spot).
// MODE 0: store bf16; 1: relu bf16; 2: relu+mean K=2 -> bf16 [n][32]
// (LPN=32, shfl_xor 16); 3: store f32 (final, feeds logsoftmax).
template<int LPN, int MODE>
__global__ void k_gatherD(const ushort_t* __restrict__ A, const int2* __restrict__ sedge,
                          const int* __restrict__ start, const ushort_t* __restrict__ root,
                          const float* __restrict__ bias, void* __restrict__ outv,
                          int npairs) {
    const unsigned* A32 = (const unsigned*)A;
    const unsigned* R32 = (const unsigned*)root;
    int gid = blockIdx.x * blockDim.x + threadIdx.x;
    int q = gid / LPN, sub = gid % LPN;
    if (q >= npairs) return;
    int na = 2 * q, nb = 2 * q + 1;
    f32x2 bi = *(const f32x2*)&bias[2 * sub];
    f32x2 acca = unpack2(R32[(long)na * LPN + sub]) + bi;
    f32x2 accb = unpack2(R32[(long)nb * LPN + sub]) + bi;
    int ea = start[na], e1a = start[na + 1];
    int eb = start[nb], e1b = start[nb + 1];
    while (ea < e1a && eb < e1b) {
        int2 pa = sedge[ea]; int2 pb = sedge[eb];
        f32x2 va = unpack2(A32[(long)pa.x * LPN + sub]);
        f32x2 vb = unpack2(A32[(long)pb.x * LPN + sub]);
        float wa = __int_as_float(pa.y), wb = __int_as_float(pb.y);
        acca[0] = fmaf(va[0], wa, acca[0]); acca[1] = fmaf(va[1], wa, acca[1]);
        accb[0] = fmaf(vb[0], wb, accb[0]); accb[1] = fmaf(vb[1], wb, accb[1]);
        ++ea; ++eb;
    }
    for (; ea < e1a; ++ea) {
        int2 p = sedge[ea];
        f32x2 v = unpack2(A32[(long)p.x * LPN + sub]);
        float w = __int_as_float(p.y);
        acca[0] = fmaf(v[0], w, acca[0]); acca[1] = fmaf(v[1], w, acca[1]);
    }
    for (; eb < e1b; ++eb) {
        int2 p = sedge[eb];
        f32x2 v = unpack2(A32[(long)p.x * LPN + sub]);
        float w = __int_as_float(p.y);
        accb[0] = fmaf(v[0], w, accb[0]); accb[1] = fmaf(v[1], w, accb[1]);
    }
    if (MODE == 3) {
        float* out = (float*)outv;
        *(f32x2*)&out[(long)na * 2 * LPN + 2 * sub] = acca;
        *(f32x2*)&out[(long)nb * 2 * LPN + 2 * sub] = accb;
    } else if (MODE == 2) {
        unsigned* out = (unsigned*)outv;
        float a0 = fmaxf(acca[0], 0.f), a1 = fmaxf(acca[1], 0.f);
        float b0 = fmaxf(accb[0], 0.f), b1 = fmaxf(accb[1], 0.f);
        float oa0 = __shfl_xor(a0, 16), oa1 = __shfl_xor(a1, 16);
        float ob0 = __shfl_xor(b0, 16), ob1 = __shfl_xor(b1, 16);
        if (sub < 16) {
            unsigned pka = (unsigned)f2bf(0.5f * (a0 + oa0)) |
                           ((unsigned)f2bf(0.5f * (a1 + oa1)) << 16);
            unsigned pkb = (unsigned)f2bf(0.5f * (b0 + ob0)) |
                           ((unsigned)f2bf(0.5f * (b1 + ob1)) << 16);
            out[(long)na * 16 + sub] = pka;
            out[(long)nb * 16 + sub] = pkb;
        }
    } else {
        unsigned* out = (unsigned*)outv;
        float a0 = acca[0], a1 = acca[1], b0 = accb[0], b1 = accb[1];
        if (MODE == 1) {
            a0 = fmaxf(a0, 0.f); a1 = fmaxf(a1, 0.f);
            b0 = fmaxf(b0, 0.f); b1 = fmaxf(b1, 0.f);
        }
        out[(long)na * LPN + sub] = (unsigned)f2bf(a0) | ((unsigned)f2bf(a1) << 16);
        out[(long)nb * LPN + sub] = (unsigned)f2bf(b0) | ((unsigned)f2bf(b1) << 16);
    }
}

// ---- conv2 epilogue: mean over K + row log_softmax (40 classes) ------------
__global__ void k_logsoftmax(const float* __restrict__ B, float* __restrict__ out, int n) {
    int gid  = blockIdx.x * blockDim.x + threadIdx.x;
    int wave = gid >> 6;
    int lane = gid & 63;
    if (wave >= n) return;
    float v = -INFINITY;
    if (lane < 40)
        v = 0.5f * (B[(long)wave * 80 + lane] + B[(long)wave * 80 + 40 + lane]);
    float m = v;
#pragma unroll
    for (int o = 32; o; o >>= 1) m = fmaxf(m, __shfl_xor(m, o));
    float ex = (lane < 40) ? expf(v - m) : 0.0f;
    float s = ex;
#pragma unroll
    for (int o = 32; o; o >>= 1) s += __shfl_xor(s, o);
    if (lane < 40) out[(long)wave * 40 + lane] = v - m - logf(s);
}

// ---------------------------------------------------------------------------
extern "C" void kernel_launch(void* const* d_in, const int* in_sizes, int n_in,
                              void* d_out, int out_size, void* d_ws, size_t ws_size,
                              hipStream_t stream) {
    const float* x       = (const float*)d_in[0];
    const int*   eidx    = (const int*)d_in[1];
    const float* w1_init = (const float*)d_in[2];
    const float* w1_deep = (const float*)d_in[3];
    const float* w1_root = (const float*)d_in[4];
    const float* b1      = (const float*)d_in[5];
    const float* w2_init = (const float*)d_in[6];
    const float* w2_deep = (const float*)d_in[7];
    const float* w2_root = (const float*)d_in[8];
    const float* b2      = (const float*)d_in[9];
    float* out = (float*)d_out;

    const int N = in_sizes[0] / 128;
    const int E = in_sizes[1] / 2;
    const int* row = eidx;
    const int* col = eidx + E;

    // workspace layout (Bh followed by rootb so deep2's padded-K overrun
    // reads stay in-bounds)
    int2*     sedge  = (int2*)d_ws;                   // E
    int*      start  = (int*)(sedge + E);             // N+8 (padded for align)
    ushort_t* A      = (ushort_t*)(start + N + 8);    // [N][<=80] bf16 messages
    ushort_t* Bh     = A + (long)N * 80;              // [N][<=80] bf16 gather out
    ushort_t* rootb  = Bh + (long)N * 80;             // [N][<=80] bf16 root
    float*    Bf     = (float*)(rootb + (long)N * 80);// [N][80] f32 (final only)
    ushort_t* Wt1    = (ushort_t*)(Bf + (long)N * 80);// 128*128 bf16
    ushort_t* Wt2    = Wt1 + 128 * 128;               // 160*32
    ushort_t* Wtd1   = Wt2 + 160 * 32;                // 64*64
    ushort_t* Wtd2   = Wtd1 + 64 * 64;                // 80*96
    int*      deg_i  = (int*)(Wtd2 + 80 * 96);        // N   (transient)
    int*      cursor = deg_i + N;                     // N   (transient)
    int*      bsum   = cursor + N;                    // 256 (transient)
    int*      bscan  = bsum + 256;                    // 256 (transient)
    float*    dinv   = (float*)(bscan + 256);         // N   (transient)
    ushort_t* h      = Bh;                            // [N][32] bf16, aliases Bh

    const int BS = 256;
    auto cdiv = [](long a, long b) { return (int)((a + b - 1) / b); };
    const int NP = N / 2;          // node pairs (N even)
    const int MT = cdiv(N, 16);    // M-tiles (N % 16 == 0)

    // ---- CSC build + weight prep ----
    hipMemsetAsync(deg_i, 0, (size_t)N * 4, stream);
    k_hist<<<cdiv(E, BS), BS, 0, stream>>>(col, deg_i, E);
    k_dinv<<<cdiv(N, BS), BS, 0, stream>>>(deg_i, dinv, N);
    k_scan1<<<256, 256, 0, stream>>>(deg_i, start, bsum, N);
    k_scan2<<<1, 256, 0, stream>>>(bsum, bscan);
    k_scan3<<<256, 256, 0, stream>>>(start, cursor, bscan, N);
    k_sort<<<cdiv(E, BS), BS, 0, stream>>>(row, col, dinv, cursor, sedge, E);
    k_wprep<<<cdiv(2 * 2 * 32 * 128, BS), BS, 0, stream>>>(w1_init, w1_root, Wt1, 2, 128, 32);
    k_wprep<<<cdiv(2 * 2 * 40 * 32, BS), BS, 0, stream>>>(w2_init, w2_root, Wt2, 2, 32, 40);
    k_wprep_diag<<<cdiv(64 * 64, BS), BS, 0, stream>>>(w1_deep, Wtd1, 2, 32, 64);
    k_wprep_diag<<<cdiv(80 * 96, BS), BS, 0, stream>>>(w2_deep, Wtd2, 2, 40, 96);

    // ---- conv1: 128 -> 32, K=2 (KF=64), relu ----
    k_mfma_gemm<float, 128, 128, 8, 64, true><<<cdiv(MT, 4), 256, 0, stream>>>(x, Wt1, A, rootb, N);
    k_gatherD<32, 1><<<cdiv((long)NP * 32, BS), BS, 0, stream>>>(A, sedge, start, rootb, b1, Bh, NP);
    k_mfma_gemm<ushort_t, 64, 64, 4, 64, false><<<cdiv(MT, 4), 256, 0, stream>>>(Bh, Wtd1, A, nullptr, N);
    k_gatherD<32, 2><<<cdiv((long)NP * 32, BS), BS, 0, stream>>>(A, sedge, start, rootb, b1, h, NP);

    // ---- conv2: 32 -> 40, K=2 (KF=80), no act ----
    k_mfma_gemm<ushort_t, 32, 32, 10, 80, true><<<cdiv(MT, 4), 256, 0, stream>>>(h, Wt2, A, rootb, N);
    k_gatherD<40, 0><<<cdiv((long)NP * 40, 320), 320, 0, stream>>>(A, sedge, start, rootb, b2, Bh, NP);
    k_mfma_gemm<ushort_t, 80, 96, 5, 80, false><<<cdiv(MT, 4), 256, 0, stream>>>(Bh, Wtd2, A, nullptr, N);
    k_gatherD<40, 3><<<cdiv((long)NP * 40, 320), 320, 0, stream>>>(A, sedge, start, rootb, b2, Bf, NP);

    // ---- epilogue: mean over K + log_softmax ----
    k_logsoftmax<<<cdiv((long)N * 64, BS), BS, 0, stream>>>(Bf, out, N);
}

// Round 14
// 389.393 us; speedup vs baseline: 1.5508x; 1.1157x over previous
//
#include <hip/hip_runtime.h>
#include <math.h>

// ---------------------------------------------------------------------------
// ARMA GNN forward: gcn_norm -> ARMAConv(128->32,K=2,T=2,relu) -> relu ->
//                   ARMAConv(32->40,K=2,T=2) -> log_softmax
// CSC gather propagation: dual-chain, 4B packed edges (u16 row | bf16 weight),
// sedge prefetch pipeline; bf16 everywhere between kernels; MFMA GEMMs.
// ---------------------------------------------------------------------------

typedef unsigned short ushort_t;
typedef __attribute__((ext_vector_type(8))) short  short8v;   // 8 bf16 (4 VGPR)
typedef __attribute__((ext_vector_type(4))) float  float4v;   // C/D frag
typedef __attribute__((ext_vector_type(2))) float  f32x2;

__device__ inline ushort_t f2bf(float v) {           // RNE f32 -> bf16
    unsigned u = __float_as_uint(v);
    u += 0x7FFFu + ((u >> 16) & 1u);
    return (ushort_t)(u >> 16);
}
__device__ inline unsigned f2bf_hi(float v) {        // RNE, bf16 in HIGH 16 bits
    unsigned u = __float_as_uint(v);
    return (u + 0x7FFFu + ((u >> 16) & 1u)) & 0xFFFF0000u;
}
__device__ inline f32x2 unpack2(unsigned p) {        // 2 packed bf16 -> f32x2
    f32x2 r;
    r[0] = __uint_as_float(p << 16);
    r[1] = __uint_as_float(p & 0xFFFF0000u);
    return r;
}
__device__ inline float bfu(ushort_t u) { return __uint_as_float((unsigned)u << 16); }

// ---- CSC build ------------------------------------------------------------
__global__ void k_hist(const int* __restrict__ col, int* __restrict__ deg, int e) {
    int i = blockIdx.x * blockDim.x + threadIdx.x;
    if (i < e) atomicAdd(&deg[col[i]], 1);
}

// scan stage 1 + dinv fused (deg read once)
__global__ void k_scan1(const int* __restrict__ deg, int* __restrict__ start,
                        int* __restrict__ bsum, float* __restrict__ dinv, int n) {
    __shared__ int s[256];
    int t = threadIdx.x, idx = blockIdx.x * 256 + t;
    int v = (idx < n) ? deg[idx] : 0;
    if (idx < n) dinv[idx] = v > 0 ? rsqrtf((float)v) : 0.0f;
    s[t] = v; __syncthreads();
    for (int o = 1; o < 256; o <<= 1) {
        int x = (t >= o) ? s[t - o] : 0;
        __syncthreads(); s[t] += x; __syncthreads();
    }
    if (idx <= n) start[idx] = s[t] - v;
    if (t == 255) bsum[blockIdx.x] = s[255];
}

__global__ void k_scan2(const int* __restrict__ bsum, int* __restrict__ bscan) {
    __shared__ int s[256];
    int t = threadIdx.x;
    int v = bsum[t]; s[t] = v; __syncthreads();
    for (int o = 1; o < 256; o <<= 1) {
        int x = (t >= o) ? s[t - o] : 0;
        __syncthreads(); s[t] += x; __syncthreads();
    }
    bscan[t] = s[t] - v;
}

__global__ void k_scan3(int* __restrict__ start, int* __restrict__ cursor,
                        const int* __restrict__ bscan, int n) {
    int idx = blockIdx.x * 256 + threadIdx.x;
    if (idx <= n) {
        int v = start[idx] + bscan[idx >> 8];
        start[idx] = v;
        if (idx < n) cursor[idx] = v;
    }
}

// bucket-scatter edges by col; pack (u16 row | bf16 weight in high bits)
__global__ void k_sort(const int* __restrict__ row, const int* __restrict__ col,
                       const float* __restrict__ dinv, int* __restrict__ cursor,
                       unsigned* __restrict__ sedge, int e) {
    int i = blockIdx.x * blockDim.x + threadIdx.x;
    if (i < e) {
        int r = row[i], c = col[i];
        int pos = atomicAdd(&cursor[c], 1);
        sedge[pos] = f2bf_hi(dinv[r] * dinv[c]) | (unsigned)r;   // r < 65536
    }
}

// ---- fused weight prep (all four Wt tables in one dispatch) ----------------
__device__ inline void wprep_body(const float* wi, const float* wr,
                                  ushort_t* Wt, int idx, int K, int F, int H) {
    int f = idx % F, colx = idx / F;
    int KH = K * H;
    const float* src = (colx < KH) ? wi : wr;
    int c = (colx < KH) ? colx : colx - KH;
    int k = c / H, h = c % H;
    Wt[idx] = f2bf(src[((long)k * F + f) * H + h]);
}
__device__ inline void wprep_diag_body(const float* w, ushort_t* Wt,
                                       int idx, int K, int F, int FPAD) {
    int kin = idx % FPAD, colx = idx / FPAD;
    int k = colx / F, h = colx % F;
    float v = 0.0f;
    if (kin < K * F) {
        int kp = kin / F, f = kin % F;
        if (kp == k) v = w[((long)k * F + f) * F + h];
    }
    Wt[idx] = f2bf(v);
}
__global__ void k_wprep_all(const float* wi1, const float* wr1, const float* wd1,
                            const float* wi2, const float* wr2, const float* wd2,
                            ushort_t* Wt1, ushort_t* Wt2,
                            ushort_t* Wtd1, ushort_t* Wtd2) {
    int idx = blockIdx.x * blockDim.x + threadIdx.x;
    if (idx < 16384) {                       // 2*2*32*128
        wprep_body(wi1, wr1, Wt1, idx, 2, 128, 32);
    } else if (idx < 16384 + 5120) {         // 2*2*40*32
        wprep_body(wi2, wr2, Wt2, idx - 16384, 2, 32, 40);
    } else if (idx < 16384 + 5120 + 4096) {  // 2*32*64
        wprep_diag_body(wd1, Wtd1, idx - 16384 - 5120, 2, 32, 64);
    } else if (idx < 16384 + 5120 + 4096 + 7680) {  // 2*40*96
        wprep_diag_body(wd2, Wtd2, idx - 16384 - 5120 - 4096, 2, 40, 96);
    }
}

// ---- MFMA GEMM: C[n, NCOLT*16] = X[n, FIN] @ Wt^T --------------------------
// XT = float or ushort_t (bf16). SPLIT: cols >= KF0 -> rootb bf16.
template<typename XT, int FIN, int FPAD, int NCOLT, int KF0, bool SPLIT>
__global__ void k_mfma_gemm(const XT* __restrict__ X,
                            const ushort_t* __restrict__ Wt,
                            ushort_t* __restrict__ out0,
                            ushort_t* __restrict__ rootb,
                            int n) {
    constexpr int KSTEPS = FPAD / 32;
    int wid  = (blockIdx.x * blockDim.x + threadIdx.x) >> 6;
    int lane = threadIdx.x & 63;
    int m0 = wid * 16;
    if (m0 >= n) return;
    int r = lane & 15, g = lane >> 4;        // A row / D col = r ; k-group = g
    float4v acc[NCOLT];
#pragma unroll
    for (int c = 0; c < NCOLT; ++c) acc[c] = (float4v){0.f, 0.f, 0.f, 0.f};
#pragma unroll
    for (int ks = 0; ks < KSTEPS; ++ks) {
        int kb = ks * 32 + g * 8;
        short8v af;
        if constexpr (sizeof(XT) == 2) {
            af = *(const short8v*)&X[(long)(m0 + r) * FIN + kb];
        } else {
            const float* xr = (const float*)X + (long)(m0 + r) * FIN + kb;
            float4 x0 = *(const float4*)xr;
            float4 x1 = *(const float4*)(xr + 4);
            af[0] = (short)f2bf(x0.x); af[1] = (short)f2bf(x0.y);
            af[2] = (short)f2bf(x0.z); af[3] = (short)f2bf(x0.w);
            af[4] = (short)f2bf(x1.x); af[5] = (short)f2bf(x1.y);
            af[6] = (short)f2bf(x1.z); af[7] = (short)f2bf(x1.w);
        }
#pragma unroll
        for (int c = 0; c < NCOLT; ++c) {
            short8v bf = *(const short8v*)&Wt[(long)(c * 16 + r) * FPAD + kb];
            acc[c] = __builtin_amdgcn_mfma_f32_16x16x32_bf16(af, bf, acc[c], 0, 0, 0);
        }
    }
#pragma unroll
    for (int c = 0; c < NCOLT; ++c) {
        int colx = c * 16 + r;
#pragma unroll
        for (int i = 0; i < 4; ++i) {
            long node = m0 + g * 4 + i;
            ushort_t val = f2bf(acc[c][i]);
            if (!SPLIT || colx < KF0)
                out0[node * KF0 + colx] = val;
            else
                rootb[node * KF0 + (colx - KF0)] = val;
        }
    }
}

// ---- dual-chain gather, packed 4B edges, sedge prefetch pipeline -----------
// LPN lanes/node (2 bf16 feats each), 2 nodes/thread, 2 random rows in flight.
// MODE 0: store bf16; 1: relu bf16; 2: relu+mean K=2 -> bf16 [n][32] (LPN=32).
#define GCONS(s, acc) {                                                   \
    f32x2 v_ = unpack2(A32[(long)((s) & 0xFFFFu) * LPN + sub]);           \
    float w_ = __uint_as_float((s) & 0xFFFF0000u);                        \
    acc[0] = fmaf(v_[0], w_, acc[0]); acc[1] = fmaf(v_[1], w_, acc[1]); }

template<int LPN, int MODE>
__global__ void k_gatherD(const ushort_t* __restrict__ A,
                          const unsigned* __restrict__ sedge,
                          const int* __restrict__ start,
                          const ushort_t* __restrict__ root,
                          const float* __restrict__ bias,
                          unsigned* __restrict__ out, int npairs) {
    const unsigned* A32 = (const unsigned*)A;
    const unsigned* R32 = (const unsigned*)root;
    int gid = blockIdx.x * blockDim.x + threadIdx.x;
    int q = gid / LPN, sub = gid % LPN;
    if (q >= npairs) return;
    int na = 2 * q, nb = 2 * q + 1;
    f32x2 bi = *(const f32x2*)&bias[2 * sub];
    f32x2 acca = unpack2(R32[(long)na * LPN + sub]) + bi;
    f32x2 accb = unpack2(R32[(long)nb * LPN + sub]) + bi;
    int ea = start[na], e1a = start[na + 1];
    int eb = start[nb], e1b = start[nb + 1];
    if (ea < e1a && eb < e1b) {
        unsigned sa = sedge[ea], sb = sedge[eb];
        while (ea + 1 < e1a && eb + 1 < e1b) {
            unsigned ta = sedge[ea + 1], tb = sedge[eb + 1];  // prefetch next
            GCONS(sa, acca); GCONS(sb, accb);
            sa = ta; sb = tb; ++ea; ++eb;
        }
        GCONS(sa, acca); GCONS(sb, accb);
        ++ea; ++eb;
    }
    for (; ea < e1a; ++ea) { unsigned s = sedge[ea]; GCONS(s, acca); }
    for (; eb < e1b; ++eb) { unsigned s = sedge[eb]; GCONS(s, accb); }
    if (MODE == 2) {
        float a0 = fmaxf(acca[0], 0.f), a1 = fmaxf(acca[1], 0.f);
        float b0 = fmaxf(accb[0], 0.f), b1 = fmaxf(accb[1], 0.f);
        float oa0 = __shfl_xor(a0, 16), oa1 = __shfl_xor(a1, 16);
        float ob0 = __shfl_xor(b0, 16), ob1 = __shfl_xor(b1, 16);
        if (sub < 16) {
            out[(long)na * 16 + sub] = (unsigned)f2bf(0.5f * (a0 + oa0)) |
                                       ((unsigned)f2bf(0.5f * (a1 + oa1)) << 16);
            out[(long)nb * 16 + sub] = (unsigned)f2bf(0.5f * (b0 + ob0)) |
                                       ((unsigned)f2bf(0.5f * (b1 + ob1)) << 16);
        }
    } else {
        float a0 = acca[0], a1 = acca[1], b0 = accb[0], b1 = accb[1];
        if (MODE == 1) {
            a0 = fmaxf(a0, 0.f); a1 = fmaxf(a1, 0.f);
            b0 = fmaxf(b0, 0.f); b1 = fmaxf(b1, 0.f);
        }
        out[(long)na * LPN + sub] = (unsigned)f2bf(a0) | ((unsigned)f2bf(a1) << 16);
        out[(long)nb * LPN + sub] = (unsigned)f2bf(b0) | ((unsigned)f2bf(b1) << 16);
    }
}

// ---- conv2 epilogue: mean over K + row log_softmax (40 classes), bf16 in ---
__global__ void k_logsoftmax(const ushort_t* __restrict__ B, float* __restrict__ out, int n) {
    int gid  = blockIdx.x * blockDim.x + threadIdx.x;
    int wave = gid >> 6;
    int lane = gid & 63;
    if (wave >= n) return;
    float v = -INFINITY;
    if (lane < 40)
        v = 0.5f * (bfu(B[(long)wave * 80 + lane]) + bfu(B[(long)wave * 80 + 40 + lane]));
    float m = v;
#pragma unroll
    for (int o = 32; o; o >>= 1) m = fmaxf(m, __shfl_xor(m, o));
    float ex = (lane < 40) ? expf(v - m) : 0.0f;
    float s = ex;
#pragma unroll
    for (int o = 32; o; o >>= 1) s += __shfl_xor(s, o);
    if (lane < 40) out[(long)wave * 40 + lane] = v - m - logf(s);
}

// ---------------------------------------------------------------------------
extern "C" void kernel_launch(void* const* d_in, const int* in_sizes, int n_in,
                              void* d_out, int out_size, void* d_ws, size_t ws_size,
                              hipStream_t stream) {
    const float* x       = (const float*)d_in[0];
    const int*   eidx    = (const int*)d_in[1];
    const float* w1_init = (const float*)d_in[2];
    const float* w1_deep = (const float*)d_in[3];
    const float* w1_root = (const float*)d_in[4];
    const float* b1      = (const float*)d_in[5];
    const float* w2_init = (const float*)d_in[6];
    const float* w2_deep = (const float*)d_in[7];
    const float* w2_root = (const float*)d_in[8];
    const float* b2      = (const float*)d_in[9];
    float* out = (float*)d_out;

    const int N = in_sizes[0] / 128;
    const int E = in_sizes[1] / 2;
    const int* row = eidx;
    const int* col = eidx + E;

    // workspace layout (Bh followed by rootb so deep2's padded-K overrun
    // reads stay in-bounds)
    unsigned* sedge  = (unsigned*)d_ws;               // E (packed 4B edges)
    int*      start  = (int*)(sedge + E);             // N+8 (padded for align)
    ushort_t* A      = (ushort_t*)(start + N + 8);    // [N][<=80] bf16 messages
    ushort_t* Bh     = A + (long)N * 80;              // [N][<=80] bf16 gather out
    ushort_t* rootb  = Bh + (long)N * 80;             // [N][<=80] bf16 root
    ushort_t* Wt1    = rootb + (long)N * 80;          // 128*128 bf16
    ushort_t* Wt2    = Wt1 + 128 * 128;               // 160*32
    ushort_t* Wtd1   = Wt2 + 160 * 32;                // 64*64
    ushort_t* Wtd2   = Wtd1 + 64 * 64;                // 80*96
    int*      deg_i  = (int*)(Wtd2 + 80 * 96);        // N   (transient)
    int*      cursor = deg_i + N;                     // N   (transient)
    int*      bsum   = cursor + N;                    // 256 (transient)
    int*      bscan  = bsum + 256;                    // 256 (transient)
    float*    dinv   = (float*)(bscan + 256);         // N   (transient)
    ushort_t* h      = Bh;                            // [N][32] bf16, aliases Bh

    const int BS = 256;
    auto cdiv = [](long a, long b) { return (int)((a + b - 1) / b); };
    const int NP = N / 2;          // node pairs (N even)
    const int MT = cdiv(N, 16);    // M-tiles (N % 16 == 0)

    // ---- CSC build + weight prep ----
    hipMemsetAsync(deg_i, 0, (size_t)N * 4, stream);
    k_hist<<<cdiv(E, BS), BS, 0, stream>>>(col, deg_i, E);
    k_scan1<<<256, 256, 0, stream>>>(deg_i, start, bsum, dinv, N);
    k_scan2<<<1, 256, 0, stream>>>(bsum, bscan);
    k_scan3<<<256, 256, 0, stream>>>(start, cursor, bscan, N);
    k_sort<<<cdiv(E, BS), BS, 0, stream>>>(row, col, dinv, cursor, sedge, E);
    k_wprep_all<<<cdiv(33280, BS), BS, 0, stream>>>(w1_init, w1_root, w1_deep,
                                                    w2_init, w2_root, w2_deep,
                                                    Wt1, Wt2, Wtd1, Wtd2);

    // ---- conv1: 128 -> 32, K=2 (KF=64), relu ----
    k_mfma_gemm<float, 128, 128, 8, 64, true><<<cdiv(MT, 4), 256, 0, stream>>>(x, Wt1, A, rootb, N);
    k_gatherD<32, 1><<<cdiv((long)NP * 32, BS), BS, 0, stream>>>(A, sedge, start, rootb, b1, (unsigned*)Bh, NP);
    k_mfma_gemm<ushort_t, 64, 64, 4, 64, false><<<cdiv(MT, 4), 256, 0, stream>>>(Bh, Wtd1, A, nullptr, N);
    k_gatherD<32, 2><<<cdiv((long)NP * 32, BS), BS, 0, stream>>>(A, sedge, start, rootb, b1, (unsigned*)h, NP);

    // ---- conv2: 32 -> 40, K=2 (KF=80), no act ----
    k_mfma_gemm<ushort_t, 32, 32, 10, 80, true><<<cdiv(MT, 4), 256, 0, stream>>>(h, Wt2, A, rootb, N);
    k_gatherD<40, 0><<<cdiv((long)NP * 40, 320), 320, 0, stream>>>(A, sedge, start, rootb, b2, (unsigned*)Bh, NP);
    k_mfma_gemm<ushort_t, 80, 96, 5, 80, false><<<cdiv(MT, 4), 256, 0, stream>>>(Bh, Wtd2, A, nullptr, N);
    k_gatherD<40, 0><<<cdiv((long)NP * 40, 320), 320, 0, stream>>>(A, sedge, start, rootb, b2, (unsigned*)Bh, NP);

    // ---- epilogue: mean over K + log_softmax (reads bf16) ----
    k_logsoftmax<<<cdiv((long)N * 64, BS), BS, 0, stream>>>(Bh, out, N);
}